// Round 7
// baseline (142.063 us; speedup 1.0000x reference)
//
#include <hip/hip_runtime.h>
#include <stdint.h>

typedef _Float16 half8 __attribute__((ext_vector_type(8)));
typedef _Float16 half4 __attribute__((ext_vector_type(4)));
typedef float    floatx4 __attribute__((ext_vector_type(4)));

#define T_LEN 2048
#define CH 64
#define BH 32            // bs * n_heads
#define QTILE 64         // t per block (16 per wave)
#define LDP 72           // prep LDS pad (halves)
#define PTP 72           // Pt row stride (halves)
#define FRAG_BH 131072   // halves per bh per tensor (64*2048)

// direct global->LDS DMA, 16B per lane; lds pointer must be wave-uniform
__device__ __forceinline__ void load16_lds(const _Float16* g, const _Float16* l) {
    __builtin_amdgcn_global_load_lds(
        (const __attribute__((address_space(1))) uint32_t*)(uintptr_t)g,
        (__attribute__((address_space(3))) uint32_t*)(uintptr_t)l, 16, 0, 0);
}

// ---------------- pass 1: fp32 -> fp16, reorder into MFMA fragment order ----------
// Q pre-scaled by 0.125 * rescale * log2(e) so attention does raw exp2.
// QF/KF[bh][g][ks][lane][8]: g = t(or s)>>4, element = X[c = ks*32+quad*8+j][t = g*16+l15]
// VF[bh][stile64][ct*2+ks][lane][8]: element = V[c = ct*16+l15][s = stile64*64+ks*32+quad*8+j]
__global__ __launch_bounds__(256, 2)
void prep_kernel(const float* __restrict__ qkv, const float* __restrict__ rescale,
                 _Float16* __restrict__ ws)
{
    __shared__ _Float16 Qs[64][LDP];   // [t][c]
    __shared__ _Float16 Ks[64][LDP];   // [s][c]
    __shared__ _Float16 Vs[64][LDP];   // [c][s]

    const int tid  = threadIdx.x;
    const int bh   = blockIdx.y;
    const int tile = blockIdx.x;       // 64-element tile along t/s
    const int x0   = tile * 64;

    const float qscale = 0.125f * 1.4426950408889634f * rescale[0];

    const float* qp = qkv + (size_t)(bh >> 3) * (1536 * T_LEN)
                          + (size_t)(bh & 7) * (192 * T_LEN);
    const float* kp = qp + 64 * T_LEN;
    const float* vp = qp + 128 * T_LEN;

    // Q,K: 4x4 register-block transpose [c][t] -> [t][c]
    {
        const int a4 = (tid & 15) * 4;
        const int c4 = (tid >> 4) * 4;
        float4 rq[4], rk[4];
#pragma unroll
        for (int i = 0; i < 4; ++i) {
            rq[i] = *(const float4*)(qp + (size_t)(c4 + i) * T_LEN + x0 + a4);
            rk[i] = *(const float4*)(kp + (size_t)(c4 + i) * T_LEN + x0 + a4);
        }
#pragma unroll
        for (int j = 0; j < 4; ++j) {
            half4 hq, hk;
#pragma unroll
            for (int i = 0; i < 4; ++i) {
                hq[i] = (_Float16)((&rq[i].x)[j] * qscale);
                hk[i] = (_Float16)((&rk[i].x)[j]);
            }
            *(half4*)&Qs[a4 + j][c4] = hq;
            *(half4*)&Ks[a4 + j][c4] = hk;
        }
        // V natural [c][s]
        const int s4 = (tid & 15) * 4;
        const int cv = tid >> 4;
#pragma unroll
        for (int i = 0; i < 4; ++i) {
            const int c = cv + 16 * i;
            float4 r = *(const float4*)(vp + (size_t)c * T_LEN + x0 + s4);
            half4 h; h[0]=(_Float16)r.x; h[1]=(_Float16)r.y; h[2]=(_Float16)r.z; h[3]=(_Float16)r.w;
            *(half4*)&Vs[c][s4] = h;
        }
    }
    __syncthreads();

    const int lane = tid & 63, wave = tid >> 6;
    const int l15 = lane & 15, quad = lane >> 4;
    _Float16* qf = ws;
    _Float16* kf = ws + (size_t)BH * FRAG_BH;
    _Float16* vf = ws + (size_t)2 * BH * FRAG_BH;

#pragma unroll
    for (int ks = 0; ks < 2; ++ks) {
        half8 hq = *(const half8*)&Qs[wave * 16 + l15][ks * 32 + quad * 8];
        half8 hk = *(const half8*)&Ks[wave * 16 + l15][ks * 32 + quad * 8];
        half8 hv = *(const half8*)&Vs[wave * 16 + l15][ks * 32 + quad * 8];
        const size_t gqk = (((size_t)bh * 128 + tile * 4 + wave) * 2 + ks) * 512 + lane * 8;
        *(half8*)(qf + gqk) = hq;
        *(half8*)(kf + gqk) = hk;
        *(half8*)(vf + (((size_t)bh * 32 + tile) * 8 + wave * 2 + ks) * 512 + lane * 8) = hv;
    }
}

// ---------------- pass 2: attention ------------------------------------------------
// 4 waves x 16 t; grid 1024 -> 4 blocks/CU, so each SIMD hosts 4 waves from 4
// INDEPENDENT blocks (separate barrier groups) -> 4-deep latency hiding for the
// stage-serial chain (the R6-identified bottleneck). K staged once per block via
// global_load_lds (double-buffered); V read directly from global (same addresses
// across the block's 4 waves -> L1-served). One barrier per iteration.
__global__ __launch_bounds__(256, 4)
void attn_kernel(const _Float16* __restrict__ ws, float* __restrict__ out)
{
    __shared__ _Float16 KL[2][4096];      // 8 KB per buf: [g_rel*2+ks][512]
    __shared__ _Float16 Pt[4][16][PTP];   // per wave: [t_rel 16][s_rel 64]

    const int tid  = threadIdx.x;
    const int wave = tid >> 6;
    const int lane = tid & 63;
    const int l15  = lane & 15;
    const int quad = lane >> 4;

    const int bh = blockIdx.y;
    const int t0 = blockIdx.x * QTILE;

    const _Float16* qf = ws;
    const _Float16* kf = ws + (size_t)BH * FRAG_BH;
    const _Float16* vf = ws + (size_t)2 * BH * FRAG_BH;
    float* op = out + (size_t)bh * (CH * T_LEN);

    const _Float16* ktile = kf + (size_t)bh * FRAG_BH;   // +st*4096 per 64-s tile
    const _Float16* vfp   = vf + (size_t)bh * FRAG_BH + lane * 8;

    // Q fragments: persistent (Q pre-scaled in prep); 16 t/wave = 1 t-group
    half8 bq[2];
#pragma unroll
    for (int ks = 0; ks < 2; ++ks)
        bq[ks] = *(const half8*)(qf +
            (((size_t)bh * 128 + blockIdx.x * 4 + wave) * 2 + ks) * 512 + lane * 8);

    const floatx4 fzero = {0.f, 0.f, 0.f, 0.f};
    floatx4 oacc[4];                    // [ctile]
#pragma unroll
    for (int ct = 0; ct < 4; ++ct) oacc[ct] = fzero;
    floatx4 lacc = fzero;               // row sums via ones-MFMA

    half8 bones;
#pragma unroll
    for (int i = 0; i < 8; ++i) bones[i] = (_Float16)1.0f;

    // ---- prologue: stage K tile 0 into buf 0 (each wave: 2KB)
#pragma unroll
    for (int c = 0; c < 2; ++c)
        load16_lds(ktile + wave * 1024 + c * 512 + lane * 8, &KL[0][wave * 1024 + c * 512]);
    __syncthreads();   // vmcnt drain: tile 0 visible

#pragma unroll 1
    for (int st = 0; st < 32; ++st) {
        const int buf = st & 1;

        // V fragments: direct from global (L1/L2), issued first; consumed at PV only
        const _Float16* vcur = vfp + (size_t)st * 4096;
        half8 bv[4][2];
#pragma unroll
        for (int ct = 0; ct < 4; ++ct)
#pragma unroll
            for (int ks = 0; ks < 2; ++ks)
                bv[ct][ks] = *(const half8*)(vcur + (size_t)(ct * 2 + ks) * 512);

        // stage next K tile into other buffer (a full iter to land)
        if (st < 31) {
            const _Float16* kg = ktile + (size_t)(st + 1) * 4096;
#pragma unroll
            for (int c = 0; c < 2; ++c)
                load16_lds(kg + wave * 1024 + c * 512 + lane * 8,
                           &KL[buf ^ 1][wave * 1024 + c * 512]);
        }

        // K fragments (A for QK) from LDS
        half8 ak[4][2];
#pragma unroll
        for (int mt = 0; mt < 4; ++mt)
#pragma unroll
            for (int ks = 0; ks < 2; ++ks)
                ak[mt][ks] = *(const half8*)&KL[buf][(mt * 2 + ks) * 512 + lane * 8];

        // S^T tile: m = s (64), n = t (16/wave), k = c (64)
        floatx4 sacc[4];
#pragma unroll
        for (int mt = 0; mt < 4; ++mt) sacc[mt] = fzero;
#pragma unroll
        for (int mt = 0; mt < 4; ++mt)
#pragma unroll
            for (int ks = 0; ks < 2; ++ks)
                sacc[mt] = __builtin_amdgcn_mfma_f32_16x16x32_f16(
                    ak[mt][ks], bq[ks], sacc[mt], 0, 0, 0);

        // p = exp2(logit); lane owns t = l15 (col), s = mt*16 + quad*4 + r
#pragma unroll
        for (int mt = 0; mt < 4; ++mt) {
            half4 ph;
#pragma unroll
            for (int r = 0; r < 4; ++r)
                ph[r] = (_Float16)__builtin_amdgcn_exp2f(sacc[mt][r]);
            *(half4*)&Pt[wave][l15][mt * 16 + quad * 4] = ph;
        }

        // P as A-operand (per-wave LDS region; DS in-order guarantees write->read)
        half8 ap[2];
#pragma unroll
        for (int ks = 0; ks < 2; ++ks)
            ap[ks] = *(const half8*)&Pt[wave][l15][ks * 32 + quad * 8];

        // row-sums + PV: O (m=t, n=c)
#pragma unroll
        for (int ks = 0; ks < 2; ++ks)
            lacc = __builtin_amdgcn_mfma_f32_16x16x32_f16(ap[ks], bones, lacc, 0, 0, 0);
#pragma unroll
        for (int ct = 0; ct < 4; ++ct)
#pragma unroll
            for (int ks = 0; ks < 2; ++ks)
                oacc[ct] = __builtin_amdgcn_mfma_f32_16x16x32_f16(
                    ap[ks], bv[ct][ks], oacc[ct], 0, 0, 0);

        // all waves done reading KL[buf] + own DMA drained -> safe to restage
        __syncthreads();
    }

    // normalize + store: col = c = ct*16 + l15, rows t = t0 + wave*16 + quad*4 + r
    float linv[4];
#pragma unroll
    for (int r = 0; r < 4; ++r) linv[r] = 1.0f / lacc[r];
#pragma unroll
    for (int ct = 0; ct < 4; ++ct) {
        const int c = ct * 16 + l15;
        const int t = t0 + wave * 16 + quad * 4;
        float4 o;
#pragma unroll
        for (int r = 0; r < 4; ++r)
            (&o.x)[r] = oacc[ct][r] * linv[r];
        *(float4*)(op + (size_t)c * T_LEN + t) = o;
    }
}

extern "C" void kernel_launch(void* const* d_in, const int* in_sizes, int n_in,
                              void* d_out, int out_size, void* d_ws, size_t ws_size,
                              hipStream_t stream) {
    const float* qkv     = (const float*)d_in[0];
    const float* rescale = (const float*)d_in[1];
    float* out = (float*)d_out;
    _Float16* ws = (_Float16*)d_ws;   // needs 3*32*131072*2 B = 25.2 MB

    prep_kernel<<<dim3(32, BH), dim3(256), 0, stream>>>(qkv, rescale, ws);
    attn_kernel<<<dim3(T_LEN / QTILE, BH), dim3(256), 0, stream>>>(ws, out);
}

// Round 9
// 135.412 us; speedup vs baseline: 1.0491x; 1.0491x over previous
//
#include <hip/hip_runtime.h>
#include <stdint.h>

typedef _Float16 half8 __attribute__((ext_vector_type(8)));
typedef _Float16 half4 __attribute__((ext_vector_type(4)));
typedef __fp16   fp16x2 __attribute__((ext_vector_type(2)));
typedef float    floatx4 __attribute__((ext_vector_type(4)));

#define T_LEN 2048
#define CH 64
#define BH 32            // bs * n_heads
#define QTILE 128        // t per block (32 per wave)
#define LDP 72           // prep LDS pad (halves)
#define PTP 72           // Pt row stride (halves)
#define FRAG_BH 131072   // halves per bh per tensor (64*2048)

// direct global->LDS DMA, 16B per lane; lds pointer must be wave-uniform
__device__ __forceinline__ void load16_lds(const _Float16* g, const _Float16* l) {
    __builtin_amdgcn_global_load_lds(
        (const __attribute__((address_space(1))) uint32_t*)(uintptr_t)g,
        (__attribute__((address_space(3))) uint32_t*)(uintptr_t)l, 16, 0, 0);
}

// ---------------- pass 1: fp32 -> fp16, reorder into MFMA fragment order ----------
// Q pre-scaled by 0.125 * rescale * log2(e) so attention does raw exp2.
// QF/KF[bh][g][ks][lane][8]: g = t(or s)>>4, element = X[c = ks*32+quad*8+j][t = g*16+l15]
// VF[bh][stile64][ct*2+ks][lane][8]: element = V[c = ct*16+l15][s = stile64*64+ks*32+quad*8+j]
__global__ __launch_bounds__(256, 2)
void prep_kernel(const float* __restrict__ qkv, const float* __restrict__ rescale,
                 _Float16* __restrict__ ws)
{
    __shared__ _Float16 Qs[64][LDP];   // [t][c]
    __shared__ _Float16 Ks[64][LDP];   // [s][c]
    __shared__ _Float16 Vs[64][LDP];   // [c][s]

    const int tid  = threadIdx.x;
    const int bh   = blockIdx.y;
    const int tile = blockIdx.x;       // 64-element tile along t/s
    const int x0   = tile * 64;

    const float qscale = 0.125f * 1.4426950408889634f * rescale[0];

    const float* qp = qkv + (size_t)(bh >> 3) * (1536 * T_LEN)
                          + (size_t)(bh & 7) * (192 * T_LEN);
    const float* kp = qp + 64 * T_LEN;
    const float* vp = qp + 128 * T_LEN;

    // Q,K: 4x4 register-block transpose [c][t] -> [t][c]
    {
        const int a4 = (tid & 15) * 4;
        const int c4 = (tid >> 4) * 4;
        float4 rq[4], rk[4];
#pragma unroll
        for (int i = 0; i < 4; ++i) {
            rq[i] = *(const float4*)(qp + (size_t)(c4 + i) * T_LEN + x0 + a4);
            rk[i] = *(const float4*)(kp + (size_t)(c4 + i) * T_LEN + x0 + a4);
        }
#pragma unroll
        for (int j = 0; j < 4; ++j) {
            half4 hq, hk;
#pragma unroll
            for (int i = 0; i < 4; ++i) {
                hq[i] = (_Float16)((&rq[i].x)[j] * qscale);
                hk[i] = (_Float16)((&rk[i].x)[j]);
            }
            *(half4*)&Qs[a4 + j][c4] = hq;
            *(half4*)&Ks[a4 + j][c4] = hk;
        }
        // V natural [c][s]
        const int s4 = (tid & 15) * 4;
        const int cv = tid >> 4;
#pragma unroll
        for (int i = 0; i < 4; ++i) {
            const int c = cv + 16 * i;
            float4 r = *(const float4*)(vp + (size_t)c * T_LEN + x0 + s4);
            half4 h; h[0]=(_Float16)r.x; h[1]=(_Float16)r.y; h[2]=(_Float16)r.z; h[3]=(_Float16)r.w;
            *(half4*)&Vs[c][s4] = h;
        }
    }
    __syncthreads();

    const int lane = tid & 63, wave = tid >> 6;
    const int l15 = lane & 15, quad = lane >> 4;
    _Float16* qf = ws;
    _Float16* kf = ws + (size_t)BH * FRAG_BH;
    _Float16* vf = ws + (size_t)2 * BH * FRAG_BH;

#pragma unroll
    for (int ks = 0; ks < 2; ++ks) {
        half8 hq = *(const half8*)&Qs[wave * 16 + l15][ks * 32 + quad * 8];
        half8 hk = *(const half8*)&Ks[wave * 16 + l15][ks * 32 + quad * 8];
        half8 hv = *(const half8*)&Vs[wave * 16 + l15][ks * 32 + quad * 8];
        const size_t gqk = (((size_t)bh * 128 + tile * 4 + wave) * 2 + ks) * 512 + lane * 8;
        *(half8*)(qf + gqk) = hq;
        *(half8*)(kf + gqk) = hk;
        *(half8*)(vf + (((size_t)bh * 32 + tile) * 8 + wave * 2 + ks) * 512 + lane * 8) = hv;
    }
}

// ---------------- pass 2: attention, cross-iteration pipelined ---------------------
// R6 structure (block-shared K via global_load_lds dbuf, direct-global V, one
// barrier/iter) + P-LAG: PV(st-1) executes at the TOP of iter st from registers
// resolved last iteration, and the Pt LDS write->read round trip spans the barrier
// into the next iteration (per-wave DS in-order => no extra waits, no Pt dbuf).
__global__ __launch_bounds__(256, 2)
void attn_kernel(const _Float16* __restrict__ ws, float* __restrict__ out)
{
    __shared__ _Float16 KL[2][4096];      // 8 KB per buf: [g_rel*2+ks][512]
    __shared__ _Float16 Pt[4][32][PTP];   // per wave: [t_rel 32][s_rel 64]

    const int tid  = threadIdx.x;
    const int wave = tid >> 6;
    const int lane = tid & 63;
    const int l15  = lane & 15;
    const int quad = lane >> 4;

    const int bh = blockIdx.y;
    const int t0 = blockIdx.x * QTILE;

    const _Float16* qf = ws;
    const _Float16* kf = ws + (size_t)BH * FRAG_BH;
    const _Float16* vf = ws + (size_t)2 * BH * FRAG_BH;
    float* op = out + (size_t)bh * (CH * T_LEN);

    const _Float16* ktile = kf + (size_t)bh * FRAG_BH;   // +st*4096 per 64-s tile
    const _Float16* vfp   = vf + (size_t)bh * FRAG_BH + lane * 8;

    // Q fragments: persistent (Q pre-scaled in prep); 32 t/wave = 2 t-groups
    half8 bq[2][2];
#pragma unroll
    for (int tb = 0; tb < 2; ++tb)
#pragma unroll
        for (int ks = 0; ks < 2; ++ks)
            bq[tb][ks] = *(const half8*)(qf +
                (((size_t)bh * 128 + blockIdx.x * 8 + wave * 2 + tb) * 2 + ks) * 512 + lane * 8);

    const floatx4 fzero = {0.f, 0.f, 0.f, 0.f};
    floatx4 oacc[2][4];                 // [tb][ctile]
#pragma unroll
    for (int tb = 0; tb < 2; ++tb)
#pragma unroll
        for (int ct = 0; ct < 4; ++ct) oacc[tb][ct] = fzero;
    floatx4 lacc[2] = {fzero, fzero};   // row sums via ones-MFMA

    half8 bones;
#pragma unroll
    for (int i = 0; i < 8; ++i) bones[i] = (_Float16)1.0f;

    half8 bv[4][2];    // V(st-1) at loop top
    half8 ap[2][2];    // P(st-1) at loop top

    // helper lambda (inlined)
    auto do_qk_exp = [&](int buf) {
        half8 ak[4][2];
#pragma unroll
        for (int mt = 0; mt < 4; ++mt)
#pragma unroll
            for (int ks = 0; ks < 2; ++ks)
                ak[mt][ks] = *(const half8*)&KL[buf][(mt * 2 + ks) * 512 + lane * 8];

        floatx4 sacc[4][2];
#pragma unroll
        for (int mt = 0; mt < 4; ++mt)
#pragma unroll
            for (int tb = 0; tb < 2; ++tb) sacc[mt][tb] = fzero;
#pragma unroll
        for (int mt = 0; mt < 4; ++mt)
#pragma unroll
            for (int tb = 0; tb < 2; ++tb)
#pragma unroll
                for (int ks = 0; ks < 2; ++ks)
                    sacc[mt][tb] = __builtin_amdgcn_mfma_f32_16x16x32_f16(
                        ak[mt][ks], bq[tb][ks], sacc[mt][tb], 0, 0, 0);

        // p = exp2(logit), packed f32->f16 cvt; lane owns t=l15, s = mt*16+quad*4+r
#pragma unroll
        for (int mt = 0; mt < 4; ++mt)
#pragma unroll
            for (int tb = 0; tb < 2; ++tb) {
                fp16x2 p01 = __builtin_amdgcn_cvt_pkrtz(
                    __builtin_amdgcn_exp2f(sacc[mt][tb][0]),
                    __builtin_amdgcn_exp2f(sacc[mt][tb][1]));
                fp16x2 p23 = __builtin_amdgcn_cvt_pkrtz(
                    __builtin_amdgcn_exp2f(sacc[mt][tb][2]),
                    __builtin_amdgcn_exp2f(sacc[mt][tb][3]));
                half4 ph;
                ph[0] = (_Float16)p01[0]; ph[1] = (_Float16)p01[1];
                ph[2] = (_Float16)p23[0]; ph[3] = (_Float16)p23[1];
                *(half4*)&Pt[wave][tb * 16 + l15][mt * 16 + quad * 4] = ph;
            }
        // issue ap read now; latency spans the barrier into next iteration.
        // Per-wave DS in-order: reads execute after the writes above.
#pragma unroll
        for (int tb = 0; tb < 2; ++tb)
#pragma unroll
            for (int ks = 0; ks < 2; ++ks)
                ap[tb][ks] = *(const half8*)&Pt[wave][tb * 16 + l15][ks * 32 + quad * 8];
    };

    // ---- prologue: stage K(0), iter 0 (no PV)
#pragma unroll
    for (int c = 0; c < 2; ++c)
        load16_lds(ktile + wave * 1024 + c * 512 + lane * 8, &KL[0][wave * 1024 + c * 512]);
    __syncthreads();   // vmcnt drain: tile 0 visible

    {
#pragma unroll
        for (int ct = 0; ct < 4; ++ct)
#pragma unroll
            for (int ks = 0; ks < 2; ++ks)
                bv[ct][ks] = *(const half8*)(vfp + (size_t)(ct * 2 + ks) * 512);
#pragma unroll
        for (int c = 0; c < 2; ++c)
            load16_lds(ktile + 4096 + wave * 1024 + c * 512 + lane * 8,
                       &KL[1][wave * 1024 + c * 512]);
        do_qk_exp(0);
        __syncthreads();
    }

    // ---- main loop: iter st does PV(st-1) first (operands ready), then QK/exp(st)
#pragma unroll 2
    for (int st = 1; st < 32; ++st) {
        const int buf = st & 1;

        // new V loads first (in flight during PV+QK+exp; consumed next iter)
        half8 bvn[4][2];
        const _Float16* vcur = vfp + (size_t)st * 4096;
#pragma unroll
        for (int ct = 0; ct < 4; ++ct)
#pragma unroll
            for (int ks = 0; ks < 2; ++ks)
                bvn[ct][ks] = *(const half8*)(vcur + (size_t)(ct * 2 + ks) * 512);

        // stage K(st+1)
        if (st < 31) {
            const _Float16* kg = ktile + (size_t)(st + 1) * 4096;
#pragma unroll
            for (int c = 0; c < 2; ++c)
                load16_lds(kg + wave * 1024 + c * 512 + lane * 8,
                           &KL[buf ^ 1][wave * 1024 + c * 512]);
        }

        // PV(st-1): independent MFMA work at iteration top (hides ak ds_read latency)
#pragma unroll
        for (int tb = 0; tb < 2; ++tb)
#pragma unroll
            for (int ks = 0; ks < 2; ++ks)
                lacc[tb] = __builtin_amdgcn_mfma_f32_16x16x32_f16(ap[tb][ks], bones, lacc[tb], 0, 0, 0);
#pragma unroll
        for (int tb = 0; tb < 2; ++tb)
#pragma unroll
            for (int ct = 0; ct < 4; ++ct)
#pragma unroll
                for (int ks = 0; ks < 2; ++ks)
                    oacc[tb][ct] = __builtin_amdgcn_mfma_f32_16x16x32_f16(
                        ap[tb][ks], bv[ct][ks], oacc[tb][ct], 0, 0, 0);

        // QK + exp + Pt round-trip for st (overwrites ap for next iter)
        do_qk_exp(buf);

        // rotate V registers
#pragma unroll
        for (int ct = 0; ct < 4; ++ct)
#pragma unroll
            for (int ks = 0; ks < 2; ++ks)
                bv[ct][ks] = bvn[ct][ks];

        __syncthreads();
    }

    // ---- epilogue: PV(31)
#pragma unroll
    for (int tb = 0; tb < 2; ++tb)
#pragma unroll
        for (int ks = 0; ks < 2; ++ks)
            lacc[tb] = __builtin_amdgcn_mfma_f32_16x16x32_f16(ap[tb][ks], bones, lacc[tb], 0, 0, 0);
#pragma unroll
    for (int tb = 0; tb < 2; ++tb)
#pragma unroll
        for (int ct = 0; ct < 4; ++ct)
#pragma unroll
            for (int ks = 0; ks < 2; ++ks)
                oacc[tb][ct] = __builtin_amdgcn_mfma_f32_16x16x32_f16(
                    ap[tb][ks], bv[ct][ks], oacc[tb][ct], 0, 0, 0);

    // normalize + store: col = c = ct*16 + l15, rows t = t0 + wave*32 + tb*16 + quad*4 + r
#pragma unroll
    for (int tb = 0; tb < 2; ++tb) {
        float linv[4];
#pragma unroll
        for (int r = 0; r < 4; ++r) linv[r] = 1.0f / lacc[tb][r];
#pragma unroll
        for (int ct = 0; ct < 4; ++ct) {
            const int c = ct * 16 + l15;
            const int t = t0 + wave * 32 + tb * 16 + quad * 4;
            float4 o;
#pragma unroll
            for (int r = 0; r < 4; ++r)
                (&o.x)[r] = oacc[tb][ct][r] * linv[r];
            *(float4*)(op + (size_t)c * T_LEN + t) = o;
        }
    }
}

extern "C" void kernel_launch(void* const* d_in, const int* in_sizes, int n_in,
                              void* d_out, int out_size, void* d_ws, size_t ws_size,
                              hipStream_t stream) {
    const float* qkv     = (const float*)d_in[0];
    const float* rescale = (const float*)d_in[1];
    float* out = (float*)d_out;
    _Float16* ws = (_Float16*)d_ws;   // needs 3*32*131072*2 B = 25.2 MB

    prep_kernel<<<dim3(32, BH), dim3(256), 0, stream>>>(qkv, rescale, ws);
    attn_kernel<<<dim3(T_LEN / QTILE, BH), dim3(256), 0, stream>>>(ws, out);
}

// Round 10
// 135.309 us; speedup vs baseline: 1.0499x; 1.0008x over previous
//
#include <hip/hip_runtime.h>
#include <stdint.h>

typedef _Float16 half8 __attribute__((ext_vector_type(8)));
typedef _Float16 half4 __attribute__((ext_vector_type(4)));
typedef __fp16   fp16x2 __attribute__((ext_vector_type(2)));
typedef float    floatx4 __attribute__((ext_vector_type(4)));

#define T_LEN 2048
#define CH 64
#define BH 32            // bs * n_heads
#define QTILE 128        // t per block (32 per wave)
#define LDP 72           // prep LDS pad (halves)
#define PTP 72           // Pt row stride (halves)
#define FRAG_BH 131072   // halves per bh per tensor (64*2048)

// ---------------- pass 1: fp32 -> fp16, reorder into MFMA fragment order ----------
// Q pre-scaled by 0.125 * rescale * log2(e) so attention does raw exp2.
// QF/KF[bh][g][ks][lane][8]: g = t(or s)>>4, element = X[c = ks*32+quad*8+j][t = g*16+l15]
// VF[bh][stile64][ct*2+ks][lane][8]: element = V[c = ct*16+l15][s = stile64*64+ks*32+quad*8+j]
__global__ __launch_bounds__(256, 2)
void prep_kernel(const float* __restrict__ qkv, const float* __restrict__ rescale,
                 _Float16* __restrict__ ws)
{
    __shared__ _Float16 Qs[64][LDP];   // [t][c]
    __shared__ _Float16 Ks[64][LDP];   // [s][c]
    __shared__ _Float16 Vs[64][LDP];   // [c][s]

    const int tid  = threadIdx.x;
    const int bh   = blockIdx.y;
    const int tile = blockIdx.x;       // 64-element tile along t/s
    const int x0   = tile * 64;

    const float qscale = 0.125f * 1.4426950408889634f * rescale[0];

    const float* qp = qkv + (size_t)(bh >> 3) * (1536 * T_LEN)
                          + (size_t)(bh & 7) * (192 * T_LEN);
    const float* kp = qp + 64 * T_LEN;
    const float* vp = qp + 128 * T_LEN;

    // Q,K: 4x4 register-block transpose [c][t] -> [t][c]
    {
        const int a4 = (tid & 15) * 4;
        const int c4 = (tid >> 4) * 4;
        float4 rq[4], rk[4];
#pragma unroll
        for (int i = 0; i < 4; ++i) {
            rq[i] = *(const float4*)(qp + (size_t)(c4 + i) * T_LEN + x0 + a4);
            rk[i] = *(const float4*)(kp + (size_t)(c4 + i) * T_LEN + x0 + a4);
        }
#pragma unroll
        for (int j = 0; j < 4; ++j) {
            half4 hq, hk;
#pragma unroll
            for (int i = 0; i < 4; ++i) {
                hq[i] = (_Float16)((&rq[i].x)[j] * qscale);
                hk[i] = (_Float16)((&rk[i].x)[j]);
            }
            *(half4*)&Qs[a4 + j][c4] = hq;
            *(half4*)&Ks[a4 + j][c4] = hk;
        }
        // V natural [c][s]
        const int s4 = (tid & 15) * 4;
        const int cv = tid >> 4;
#pragma unroll
        for (int i = 0; i < 4; ++i) {
            const int c = cv + 16 * i;
            float4 r = *(const float4*)(vp + (size_t)c * T_LEN + x0 + s4);
            half4 h; h[0]=(_Float16)r.x; h[1]=(_Float16)r.y; h[2]=(_Float16)r.z; h[3]=(_Float16)r.w;
            *(half4*)&Vs[c][s4] = h;
        }
    }
    __syncthreads();

    const int lane = tid & 63, wave = tid >> 6;
    const int l15 = lane & 15, quad = lane >> 4;
    _Float16* qf = ws;
    _Float16* kf = ws + (size_t)BH * FRAG_BH;
    _Float16* vf = ws + (size_t)2 * BH * FRAG_BH;

#pragma unroll
    for (int ks = 0; ks < 2; ++ks) {
        half8 hq = *(const half8*)&Qs[wave * 16 + l15][ks * 32 + quad * 8];
        half8 hk = *(const half8*)&Ks[wave * 16 + l15][ks * 32 + quad * 8];
        half8 hv = *(const half8*)&Vs[wave * 16 + l15][ks * 32 + quad * 8];
        const size_t gqk = (((size_t)bh * 128 + tile * 4 + wave) * 2 + ks) * 512 + lane * 8;
        *(half8*)(qf + gqk) = hq;
        *(half8*)(kf + gqk) = hk;
        *(half8*)(vf + (((size_t)bh * 32 + tile) * 8 + wave * 2 + ks) * 512 + lane * 8) = hv;
    }
}

// ---------------- pass 2: attention, barrier-free, register-pipelined --------------
// NO __syncthreads in the K-loop: waves free-run and anti-phase (one wave's exp/VALU
// overlaps another's MFMA). K and V fragments are loaded per-wave directly from ws
// (the block's 4 waves read identical addresses -> L1/L2 served), each issued a FULL
// iteration before use:
//   iter st: PV(st-1)[ap,bv ready] | issue bv<-V(st) | QK(st)[ak ready] |
//            issue ak<-K(st+1) | exp->Pt->ap (per-wave LDS, DS in-order, no sync)
__global__ __launch_bounds__(256, 2)
void attn_kernel(const _Float16* __restrict__ ws, float* __restrict__ out)
{
    __shared__ _Float16 Pt[4][32][PTP];   // per wave: [t_rel 32][s_rel 64]

    const int tid  = threadIdx.x;
    const int wave = tid >> 6;
    const int lane = tid & 63;
    const int l15  = lane & 15;
    const int quad = lane >> 4;

    const int bh = blockIdx.y;
    const int t0 = blockIdx.x * QTILE;

    const _Float16* qf = ws;
    const _Float16* kf = ws + (size_t)BH * FRAG_BH;
    const _Float16* vf = ws + (size_t)2 * BH * FRAG_BH;
    float* op = out + (size_t)bh * (CH * T_LEN);

    const _Float16* kfp = kf + (size_t)bh * FRAG_BH + lane * 8;
    const _Float16* vfp = vf + (size_t)bh * FRAG_BH + lane * 8;

    // Q fragments: persistent (Q pre-scaled in prep); 32 t/wave = 2 t-groups
    half8 bq[2][2];
#pragma unroll
    for (int tb = 0; tb < 2; ++tb)
#pragma unroll
        for (int ks = 0; ks < 2; ++ks)
            bq[tb][ks] = *(const half8*)(qf +
                (((size_t)bh * 128 + blockIdx.x * 8 + wave * 2 + tb) * 2 + ks) * 512 + lane * 8);

    const floatx4 fzero = {0.f, 0.f, 0.f, 0.f};
    floatx4 oacc[2][4];                 // [tb][ctile]
#pragma unroll
    for (int tb = 0; tb < 2; ++tb)
#pragma unroll
        for (int ct = 0; ct < 4; ++ct) oacc[tb][ct] = fzero;
    floatx4 lacc[2] = {fzero, fzero};   // row sums via ones-MFMA

    half8 bones;
#pragma unroll
    for (int i = 0; i < 8; ++i) bones[i] = (_Float16)1.0f;

    half8 ak[4][2];    // K(st): loaded one iteration ahead of its QK
    half8 bv[4][2];    // V(st-1) at loop top
    half8 ap[2][2];    // P(st-1) at loop top

    // QK + exp + Pt round-trip for tile st using current ak
    auto do_qk_exp = [&]() {
        floatx4 sacc[4][2];
#pragma unroll
        for (int mt = 0; mt < 4; ++mt)
#pragma unroll
            for (int tb = 0; tb < 2; ++tb) sacc[mt][tb] = fzero;
#pragma unroll
        for (int mt = 0; mt < 4; ++mt)
#pragma unroll
            for (int tb = 0; tb < 2; ++tb)
#pragma unroll
                for (int ks = 0; ks < 2; ++ks)
                    sacc[mt][tb] = __builtin_amdgcn_mfma_f32_16x16x32_f16(
                        ak[mt][ks], bq[tb][ks], sacc[mt][tb], 0, 0, 0);

        // p = exp2(logit), packed f32->f16; lane owns t=l15, s = mt*16+quad*4+r
#pragma unroll
        for (int mt = 0; mt < 4; ++mt)
#pragma unroll
            for (int tb = 0; tb < 2; ++tb) {
                fp16x2 p01 = __builtin_amdgcn_cvt_pkrtz(
                    __builtin_amdgcn_exp2f(sacc[mt][tb][0]),
                    __builtin_amdgcn_exp2f(sacc[mt][tb][1]));
                fp16x2 p23 = __builtin_amdgcn_cvt_pkrtz(
                    __builtin_amdgcn_exp2f(sacc[mt][tb][2]),
                    __builtin_amdgcn_exp2f(sacc[mt][tb][3]));
                half4 ph;
                ph[0] = (_Float16)p01[0]; ph[1] = (_Float16)p01[1];
                ph[2] = (_Float16)p23[0]; ph[3] = (_Float16)p23[1];
                *(half4*)&Pt[wave][tb * 16 + l15][mt * 16 + quad * 4] = ph;
            }
        // ap read issued now; per-wave DS in-order => sees the writes above;
        // latency spans into the next iteration's PV.
#pragma unroll
        for (int tb = 0; tb < 2; ++tb)
#pragma unroll
            for (int ks = 0; ks < 2; ++ks)
                ap[tb][ks] = *(const half8*)&Pt[wave][tb * 16 + l15][ks * 32 + quad * 8];
    };

    // ---- prologue: tile 0
#pragma unroll
    for (int mt = 0; mt < 4; ++mt)
#pragma unroll
        for (int ks = 0; ks < 2; ++ks)
            ak[mt][ks] = *(const half8*)(kfp + (size_t)(mt * 2 + ks) * 512);
#pragma unroll
    for (int ct = 0; ct < 4; ++ct)
#pragma unroll
        for (int ks = 0; ks < 2; ++ks)
            bv[ct][ks] = *(const half8*)(vfp + (size_t)(ct * 2 + ks) * 512);
    do_qk_exp();
    // K(1) issued now (full iteration to land)
#pragma unroll
    for (int mt = 0; mt < 4; ++mt)
#pragma unroll
        for (int ks = 0; ks < 2; ++ks)
            ak[mt][ks] = *(const half8*)(kfp + 4096 + (size_t)(mt * 2 + ks) * 512);

    // ---- main loop
#pragma unroll 2
    for (int st = 1; st < 32; ++st) {
        // PV(st-1): operands resolved; independent MFMA work at iteration top
#pragma unroll
        for (int tb = 0; tb < 2; ++tb)
#pragma unroll
            for (int ks = 0; ks < 2; ++ks)
                lacc[tb] = __builtin_amdgcn_mfma_f32_16x16x32_f16(ap[tb][ks], bones, lacc[tb], 0, 0, 0);
#pragma unroll
        for (int tb = 0; tb < 2; ++tb)
#pragma unroll
            for (int ct = 0; ct < 4; ++ct)
#pragma unroll
                for (int ks = 0; ks < 2; ++ks)
                    oacc[tb][ct] = __builtin_amdgcn_mfma_f32_16x16x32_f16(
                        ap[tb][ks], bv[ct][ks], oacc[tb][ct], 0, 0, 0);

        // V(st): issue now, consumed at next iteration's PV
        const _Float16* vcur = vfp + (size_t)st * 4096;
#pragma unroll
        for (int ct = 0; ct < 4; ++ct)
#pragma unroll
            for (int ks = 0; ks < 2; ++ks)
                bv[ct][ks] = *(const half8*)(vcur + (size_t)(ct * 2 + ks) * 512);

        // QK(st) with ak (issued one iteration ago), then exp -> Pt -> ap
        do_qk_exp();

        // K(st+1): issue now, consumed at next iteration's QK
        if (st < 31) {
            const _Float16* kcur = kfp + (size_t)(st + 1) * 4096;
#pragma unroll
            for (int mt = 0; mt < 4; ++mt)
#pragma unroll
                for (int ks = 0; ks < 2; ++ks)
                    ak[mt][ks] = *(const half8*)(kcur + (size_t)(mt * 2 + ks) * 512);
        }
    }

    // ---- epilogue: PV(31)
#pragma unroll
    for (int tb = 0; tb < 2; ++tb)
#pragma unroll
        for (int ks = 0; ks < 2; ++ks)
            lacc[tb] = __builtin_amdgcn_mfma_f32_16x16x32_f16(ap[tb][ks], bones, lacc[tb], 0, 0, 0);
#pragma unroll
    for (int tb = 0; tb < 2; ++tb)
#pragma unroll
        for (int ct = 0; ct < 4; ++ct)
#pragma unroll
            for (int ks = 0; ks < 2; ++ks)
                oacc[tb][ct] = __builtin_amdgcn_mfma_f32_16x16x32_f16(
                    ap[tb][ks], bv[ct][ks], oacc[tb][ct], 0, 0, 0);

    // normalize + store: col = c = ct*16 + l15, rows t = t0 + wave*32 + tb*16 + quad*4 + r
#pragma unroll
    for (int tb = 0; tb < 2; ++tb) {
        float linv[4];
#pragma unroll
        for (int r = 0; r < 4; ++r) linv[r] = 1.0f / lacc[tb][r];
#pragma unroll
        for (int ct = 0; ct < 4; ++ct) {
            const int c = ct * 16 + l15;
            const int t = t0 + wave * 32 + tb * 16 + quad * 4;
            float4 o;
#pragma unroll
            for (int r = 0; r < 4; ++r)
                (&o.x)[r] = oacc[tb][ct][r] * linv[r];
            *(float4*)(op + (size_t)c * T_LEN + t) = o;
        }
    }
}

extern "C" void kernel_launch(void* const* d_in, const int* in_sizes, int n_in,
                              void* d_out, int out_size, void* d_ws, size_t ws_size,
                              hipStream_t stream) {
    const float* qkv     = (const float*)d_in[0];
    const float* rescale = (const float*)d_in[1];
    float* out = (float*)d_out;
    _Float16* ws = (_Float16*)d_ws;   // needs 3*32*131072*2 B = 25.2 MB

    prep_kernel<<<dim3(32, BH), dim3(256), 0, stream>>>(qkv, rescale, ws);
    attn_kernel<<<dim3(T_LEN / QTILE, BH), dim3(256), 0, stream>>>(ws, out);
}